// Round 1
// baseline (428.135 us; speedup 1.0000x reference)
//
#include <hip/hip_runtime.h>
#include <hip/hip_bf16.h>

typedef float f32x4 __attribute__((ext_vector_type(4)));
typedef short short8 __attribute__((ext_vector_type(8)));

#define BATCH 8
#define CH    128
#define HWN   50176
#define PN    128
#define KSPLIT 64
#define KWIN  784          // HWN / KSPLIT
#define BK    64
#define NST   13           // ceil(KWIN / BK), last stage has only 16 valid k

__device__ __forceinline__ ushort f2bf(float f){
  uint u = __float_as_uint(f);
  u += 0x7FFFu + ((u >> 16) & 1u);       // round-to-nearest-even
  return (ushort)(u >> 16);
}
__device__ __forceinline__ float bf2f(ushort h){
  return __uint_as_float(((uint)h) << 16);
}

// ---------------------------------------------------------------------------
// Main kernel: block = (batch b, k-split s). Computes 128x128 partial for
// k-window [s*784, (s+1)*784), via bf16 hi/lo split MFMA.
// EPI==0: write partial tile to PART.  EPI==1: atomicAdd into OUT.
// ---------------------------------------------------------------------------
template<int EPI>
__global__ __launch_bounds__(256, 2)
void raggr_kernel(const float* __restrict__ X, const float* __restrict__ Mk,
                  float* __restrict__ OUT, float* __restrict__ PART){
  __shared__ char lds[49152];
  char* Xh = lds;            // [128][64] bf16 (x hi),   128B rows, swizzled
  char* Xl = lds + 16384;    // [128][64] bf16 (x lo)
  char* Mm = lds + 32768;    // [128][64] bf16 (mask)

  const int tid  = threadIdx.x;
  const int b    = blockIdx.x >> 6;
  const int s    = blockIdx.x & 63;
  const int lane = tid & 63;
  const int wid  = tid >> 6;
  const int wrow = (wid >> 1) * 64;   // wave's output row base
  const int wcol = (wid & 1) * 64;    // wave's output col base

  const size_t base = (size_t)b * CH * HWN + (size_t)s * KWIN;
  const f32x4 z4 = {0.f, 0.f, 0.f, 0.f};

  f32x4 acc[4][4];
  #pragma unroll
  for(int m=0;m<4;++m)
    #pragma unroll
    for(int n=0;n<4;++n) acc[m][n] = z4;

  f32x4 xv[8], mv[8];

  // issue global loads for stage t into registers (branchless, clamped addr)
  #define ISSUE(tt) {                                                         \
    const int kv = (KWIN - (tt)*BK) < BK ? (KWIN - (tt)*BK) : BK;             \
    _Pragma("unroll")                                                         \
    for(int it=0; it<8; ++it){                                                \
      int f = it*256 + tid;                                                   \
      int row = f >> 4, kq = f & 15;                                          \
      bool ok = (kq*4) < kv;                                                  \
      size_t off = base + (size_t)row * HWN + (size_t)((tt)*BK + kq*4);       \
      size_t offc = ok ? off : base;                                          \
      f32x4 xt = *(const f32x4*)(X  + offc);                                  \
      f32x4 mt = *(const f32x4*)(Mk + offc);                                  \
      xv[it] = ok ? xt : z4;                                                  \
      mv[it] = ok ? mt : z4;                                                  \
    } }

  // convert regs -> bf16 hi/lo and store to swizzled LDS
  #define WRITE_LDS() {                                                       \
    _Pragma("unroll")                                                         \
    for(int it=0; it<8; ++it){                                                \
      int f = it*256 + tid;                                                   \
      int row = f >> 4, kq = f & 15;                                          \
      int boff = row*128 + ((kq*8) ^ ((row & 7) << 4));                       \
      ushort h0=f2bf(xv[it].x), h1=f2bf(xv[it].y),                            \
             h2=f2bf(xv[it].z), h3=f2bf(xv[it].w);                            \
      ushort l0=f2bf(xv[it].x - bf2f(h0)), l1=f2bf(xv[it].y - bf2f(h1)),      \
             l2=f2bf(xv[it].z - bf2f(h2)), l3=f2bf(xv[it].w - bf2f(h3));      \
      ushort m0=f2bf(mv[it].x), m1=f2bf(mv[it].y),                            \
             m2=f2bf(mv[it].z), m3=f2bf(mv[it].w);                            \
      uint2 uh; uh.x = (uint)h0 | ((uint)h1<<16); uh.y = (uint)h2 | ((uint)h3<<16); \
      uint2 ul; ul.x = (uint)l0 | ((uint)l1<<16); ul.y = (uint)l2 | ((uint)l3<<16); \
      uint2 um; um.x = (uint)m0 | ((uint)m1<<16); um.y = (uint)m2 | ((uint)m3<<16); \
      *(uint2*)(Xh + boff) = uh;                                              \
      *(uint2*)(Xl + boff) = ul;                                              \
      *(uint2*)(Mm + boff) = um;                                              \
    } }

  // one BK=64 tile: 2 k-steps of 32, 16 frags/wave, hi+lo MFMA into same acc
  #define COMPUTE() {                                                         \
    _Pragma("unroll")                                                         \
    for(int ks=0; ks<2; ++ks){                                                \
      const int kb = ks*64 + ((lane >> 4) << 4);                              \
      short8 bfr[4], ah[4], al[4];                                            \
      _Pragma("unroll")                                                       \
      for(int n=0;n<4;++n){                                                   \
        int r = wcol + n*16 + (lane & 15);                                    \
        bfr[n] = *(const short8*)(Mm + r*128 + (kb ^ ((r&7)<<4)));            \
      }                                                                       \
      _Pragma("unroll")                                                       \
      for(int m=0;m<4;++m){                                                   \
        int r = wrow + m*16 + (lane & 15);                                    \
        int o = r*128 + (kb ^ ((r&7)<<4));                                    \
        ah[m] = *(const short8*)(Xh + o);                                     \
        al[m] = *(const short8*)(Xl + o);                                     \
      }                                                                       \
      _Pragma("unroll")                                                       \
      for(int m=0;m<4;++m)                                                    \
        _Pragma("unroll")                                                     \
        for(int n=0;n<4;++n){                                                 \
          acc[m][n] = __builtin_amdgcn_mfma_f32_16x16x32_bf16(ah[m], bfr[n], acc[m][n], 0,0,0); \
          acc[m][n] = __builtin_amdgcn_mfma_f32_16x16x32_bf16(al[m], bfr[n], acc[m][n], 0,0,0); \
        }                                                                     \
    } }

  ISSUE(0);
  WRITE_LDS();
  __syncthreads();

  #pragma unroll 1
  for(int t=0; t<NST; ++t){
    if(t+1 < NST) ISSUE(t+1);     // prefetch next stage (in flight across compute)
    COMPUTE();
    __syncthreads();              // everyone done reading LDS
    if(t+1 < NST){ WRITE_LDS(); __syncthreads(); }
  }

  // epilogue — C/D layout: col = lane&15, row = (lane>>4)*4 + j  [m89]
  if(EPI == 0){
    float* p = PART + ((size_t)(b*KSPLIT + s)) * 16384;
    #pragma unroll
    for(int m=0;m<4;++m){
      int row0 = wrow + m*16 + ((lane >> 4) << 2);
      #pragma unroll
      for(int n=0;n<4;++n){
        int col = wcol + n*16 + (lane & 15);
        #pragma unroll
        for(int j=0;j<4;++j) p[(size_t)(row0+j)*128 + col] = acc[m][n][j];
      }
    }
  } else {
    float* o = OUT + (size_t)b * 16384;
    #pragma unroll
    for(int m=0;m<4;++m){
      int row0 = wrow + m*16 + ((lane >> 4) << 2);
      #pragma unroll
      for(int n=0;n<4;++n){
        int col = wcol + n*16 + (lane & 15);
        #pragma unroll
        for(int j=0;j<4;++j) atomicAdd(&o[(size_t)(row0+j)*128 + col], acc[m][n][j]);
      }
    }
  }
}

// sum 64 k-split partials -> out.  32768 threads x 1 float4 each.
__global__ void reduce_kernel(const float* __restrict__ PART, float* __restrict__ OUT){
  int idx = blockIdx.x * 256 + threadIdx.x;      // 0 .. 32767
  int b   = idx >> 12;                           // 4096 float4 per batch
  int c4  = idx & 4095;
  const f32x4* p = (const f32x4*)PART;
  f32x4 sum = {0.f,0.f,0.f,0.f};
  size_t base_ = (size_t)b * KSPLIT * 4096 + (size_t)c4;
  #pragma unroll 8
  for(int s2=0; s2<KSPLIT; ++s2) sum += p[base_ + (size_t)s2*4096];
  ((f32x4*)OUT)[idx] = sum;
}

__global__ void zero_kernel(float* __restrict__ OUT){
  int idx = blockIdx.x * 256 + threadIdx.x;
  if(idx < BATCH*CH*PN) OUT[idx] = 0.f;
}

extern "C" void kernel_launch(void* const* d_in, const int* in_sizes, int n_in,
                              void* d_out, int out_size, void* d_ws, size_t ws_size,
                              hipStream_t stream){
  const float* X  = (const float*)d_in[0];
  const float* Mk = (const float*)d_in[1];
  float* O = (float*)d_out;

  const size_t part_bytes = (size_t)BATCH * KSPLIT * CH * PN * sizeof(float); // 33.5 MB
  if(ws_size >= part_bytes && d_ws != nullptr){
    float* part = (float*)d_ws;
    raggr_kernel<0><<<dim3(BATCH*KSPLIT), dim3(256), 0, stream>>>(X, Mk, O, part);
    reduce_kernel<<<dim3(128), dim3(256), 0, stream>>>(part, O);
  } else {
    zero_kernel<<<dim3(512), dim3(256), 0, stream>>>(O);
    raggr_kernel<1><<<dim3(BATCH*KSPLIT), dim3(256), 0, stream>>>(X, Mk, O, nullptr);
  }
}